// Round 5
// baseline (271.425 us; speedup 1.0000x reference)
//
#include <hip/hip_runtime.h>

// LTC cell: B=1024, I=128, N=256, 6 unfolds.
// Round 9: R0 structure (256 blocks x 1024 thr, 4 batches/block) + two
// model-driven changes. Issue model (validated on R0/R7/R8):
// issue = 2cyc/inst + 6cyc/trans. (1) 4-WAY SHARED RCP in the recurrent
// loop: rp=rcp(a0*a1*a2*a3) -> 94 vs 100 cyc per 4 evals. Safe: update is a
// convex combination => |v|<1 => a<=2^21 => product<=2^84, no overflow.
// (2) QUAD LANE MAP (lane = n*4+ih): the 4 i-slice partials for (batch,n)
// sit in adjacent lanes -> 2-step shfl_xor in-wave reduce, no part[] LDS,
// ONE barrier per unfold (ping-pong vt[2] kills the WAR hazard). Barriers
// 13 -> 7. vt/xs padded every 64/32 rows so quad broadcasts are bank-clean
// (pad index folds to i+ih at compile time).

#define LOG2E 1.44269504088896340f

constexpr int Bn = 1024;
constexpr int In = 128;
constexpr int Nn = 256;
constexpr int UNFOLDS = 6;

#if __has_builtin(__builtin_amdgcn_exp2f)
#define EXP2F(x) __builtin_amdgcn_exp2f(x)
#else
#define EXP2F(x) __exp2f(x)
#endif
#if __has_builtin(__builtin_amdgcn_rcpf)
#define RCPF(x) __builtin_amdgcn_rcpf(x)
#else
#define RCPF(x) (1.0f / (x))
#endif

// ---------------------------------------------------------------------------
// Pack: Prec[i*N+n] = {sigma*log2e, sigma*mu*log2e, W, W*erev}; same for Psen.
// sigmoid(sigma*(v-mu)) = 1/(1 + exp2(B - A*v)), A=sigma*log2e, B=sigma*mu*log2e.
// ---------------------------------------------------------------------------
__global__ __launch_bounds__(256) void pack_kernel(
    const float* __restrict__ mu, const float* __restrict__ sigma,
    const float* __restrict__ W, const float* __restrict__ erev,
    const float* __restrict__ smu, const float* __restrict__ ssigma,
    const float* __restrict__ sW, const float* __restrict__ serev,
    float4* __restrict__ Prec, float4* __restrict__ Psen) {
    int idx = blockIdx.x * 256 + threadIdx.x;
    if (idx < Nn * Nn) {
        float s = sigma[idx], m = mu[idx], w = W[idx], e = erev[idx];
        Prec[idx] = make_float4(s * LOG2E, s * m * LOG2E, w, w * e);
        return;
    }
    int j = idx - Nn * Nn;
    if (j < In * Nn) {
        float s = ssigma[j], m = smu[j], w = sW[j], e = serev[j];
        Psen[j] = make_float4(s * LOG2E, s * m * LOG2E, w, w * e);
    }
}

// ---------------------------------------------------------------------------
// Fused LTC kernel. Grid 256 x 1024. Thread = (n = tid>>2, ih = tid&3).
// Per thread per unfold: 64 i-iters x 4 batches. Quad (4 adjacent lanes,
// same n, ih=0..3) covers 4 i-slices; reduce over slices = shfl_xor(2)+(1)
// with built-in batch selection (lane ih keeps batch ih).
// ---------------------------------------------------------------------------
__global__ __launch_bounds__(1024, 1) void ltc_fused_kernel(
    const float* __restrict__ inputs, const float* __restrict__ state,
    const float* __restrict__ input_w, const float* __restrict__ input_b,
    const float4* __restrict__ Psen, const float4* __restrict__ Prec,
    const float* __restrict__ vleak, const float* __restrict__ gleak,
    const float* __restrict__ cmt, float* __restrict__ out) {
    __shared__ float4 vt[2][260];        // ping-pong v, pad every 64 rows
    __shared__ float4 xs[132];           // sensory x, pad every 32 rows

    const int tid = threadIdx.x;
    const int b0 = blockIdx.x * 4;
    const int n  = tid >> 2;             // column 0..255 (16 per wave)
    const int ih = tid & 3;              // i-slice AND owned batch

    // ---- fill: v state + sensory x (quad layouts, padded) ----
    float vp = state[(b0 + ih) * Nn + n];
    ((float*)vt[0])[((n + (n >> 6)) << 2) + ih] = vp;
    if (tid < 512) {
        int i = tid >> 2, bb = tid & 3;
        ((float*)xs)[((i + (i >> 5)) << 2) + bb] =
            inputs[(b0 + bb) * In + i] * input_w[i] + input_b[i];
    }
    const float g = gleak[n], c = cmt[n];
    const float gvl = g * vleak[n];
    __syncthreads();

    // ---- sensory sums (32 i per lane; per-eval rcp: x is unbounded) ----
    float sens_n, sens_d;
    {
        float pn[4] = {0.f, 0.f, 0.f, 0.f};
        float pd[4] = {0.f, 0.f, 0.f, 0.f};
        const float4* __restrict__ pp = Psen + n;
#pragma unroll 8
        for (int ii = 0; ii < 32; ++ii) {
            int i = ih * 32 + ii;
            float4 p = pp[i * Nn];       // 4x256B coalesced segments
            float4 v = xs[i + ih];       // padded broadcast (i>>5 == ih)
            float r0 = RCPF(1.0f + EXP2F(fmaf(-p.x, v.x, p.y)));
            float r1 = RCPF(1.0f + EXP2F(fmaf(-p.x, v.y, p.y)));
            float r2 = RCPF(1.0f + EXP2F(fmaf(-p.x, v.z, p.y)));
            float r3 = RCPF(1.0f + EXP2F(fmaf(-p.x, v.w, p.y)));
            pd[0] += p.z * r0; pn[0] += p.w * r0;
            pd[1] += p.z * r1; pn[1] += p.w * r1;
            pd[2] += p.z * r2; pn[2] += p.w * r2;
            pd[3] += p.z * r3; pn[3] += p.w * r3;
        }
        // quad reduce: step A (xor 2) then step B (xor 1)
        const bool hi = (ih & 2) != 0;
        float sn0 = hi ? pn[0] : pn[2], sn1 = hi ? pn[1] : pn[3];
        float sd0 = hi ? pd[0] : pd[2], sd1 = hi ? pd[1] : pd[3];
        sn0 = __shfl_xor(sn0, 2); sn1 = __shfl_xor(sn1, 2);
        sd0 = __shfl_xor(sd0, 2); sd1 = __shfl_xor(sd1, 2);
        float an0 = (hi ? pn[2] : pn[0]) + sn0;
        float an1 = (hi ? pn[3] : pn[1]) + sn1;
        float ad0 = (hi ? pd[2] : pd[0]) + sd0;
        float ad1 = (hi ? pd[3] : pd[1]) + sd1;
        const bool odd = (ih & 1) != 0;
        float sn = odd ? an0 : an1, sd = odd ? ad0 : ad1;
        sn = __shfl_xor(sn, 1); sd = __shfl_xor(sd, 1);
        sens_n = (odd ? an1 : an0) + sn;
        sens_d = (odd ? ad1 : ad0) + sd;
    }

    // ---- 6 unfolds: one barrier each; 4-way shared rcp ----
    const float4* __restrict__ pp = Prec + n;
    int cur = 0;
    for (int s = 0; s < UNFOLDS; ++s) {
        __syncthreads();  // vt[cur] fully written by previous step
        float pn[4] = {0.f, 0.f, 0.f, 0.f};
        float pd[4] = {0.f, 0.f, 0.f, 0.f};
        const float4* __restrict__ vc = vt[cur];
#pragma unroll 8
        for (int ii = 0; ii < 64; ++ii) {
            int i = ih * 64 + ii;
            float4 p = pp[i * Nn];       // coalesced (L2-resident stream)
            float4 v = vc[i + ih];       // padded broadcast (i>>6 == ih)
            float a0 = 1.0f + EXP2F(fmaf(-p.x, v.x, p.y));
            float a1 = 1.0f + EXP2F(fmaf(-p.x, v.y, p.y));
            float a2 = 1.0f + EXP2F(fmaf(-p.x, v.z, p.y));
            float a3 = 1.0f + EXP2F(fmaf(-p.x, v.w, p.y));
            // |v|<1 (convex update) => a <= 2^21 => product <= 2^84: safe.
            float p01 = a0 * a1, p23 = a2 * a3;
            float rp  = RCPF(p01 * p23);
            float q01 = p23 * rp, q23 = p01 * rp;
            float r0 = a1 * q01, r1 = a0 * q01;
            float r2 = a3 * q23, r3 = a2 * q23;
            pd[0] += p.z * r0; pn[0] += p.w * r0;
            pd[1] += p.z * r1; pn[1] += p.w * r1;
            pd[2] += p.z * r2; pn[2] += p.w * r2;
            pd[3] += p.z * r3; pn[3] += p.w * r3;
        }
        // quad reduce (in-wave, no barrier)
        const bool hi = (ih & 2) != 0;
        float sn0 = hi ? pn[0] : pn[2], sn1 = hi ? pn[1] : pn[3];
        float sd0 = hi ? pd[0] : pd[2], sd1 = hi ? pd[1] : pd[3];
        sn0 = __shfl_xor(sn0, 2); sn1 = __shfl_xor(sn1, 2);
        sd0 = __shfl_xor(sd0, 2); sd1 = __shfl_xor(sd1, 2);
        float an0 = (hi ? pn[2] : pn[0]) + sn0;
        float an1 = (hi ? pn[3] : pn[1]) + sn1;
        float ad0 = (hi ? pd[2] : pd[0]) + sd0;
        float ad1 = (hi ? pd[3] : pd[1]) + sd1;
        const bool odd = (ih & 1) != 0;
        float sn = odd ? an0 : an1, sd = odd ? ad0 : ad1;
        sn = __shfl_xor(sn, 1); sd = __shfl_xor(sd, 1);
        float wn = sens_n + (odd ? an1 : an0) + sn;
        float wd = sens_d + (odd ? ad1 : ad0) + sd;

        float res = (c * vp + gvl + wn) * RCPF(c + g + wd);
        vp = res;
        if (s == UNFOLDS - 1)
            out[(b0 + ih) * Nn + n] = res;           // final store
        else
            ((float*)vt[cur ^ 1])[((n + (n >> 6)) << 2) + ih] = res;
        cur ^= 1;
    }
}

// ---------------------------------------------------------------------------
extern "C" void kernel_launch(void* const* d_in, const int* in_sizes, int n_in,
                              void* d_out, int out_size, void* d_ws, size_t ws_size,
                              hipStream_t stream) {
    const float* inputs   = (const float*)d_in[0];
    const float* state    = (const float*)d_in[1];
    const float* input_w  = (const float*)d_in[2];
    const float* input_b  = (const float*)d_in[3];
    const float* smu      = (const float*)d_in[4];
    const float* ssigma   = (const float*)d_in[5];
    const float* sW       = (const float*)d_in[6];
    const float* serev    = (const float*)d_in[7];
    const float* mu       = (const float*)d_in[8];
    const float* sigma    = (const float*)d_in[9];
    const float* W        = (const float*)d_in[10];
    const float* erev     = (const float*)d_in[11];
    const float* vleak    = (const float*)d_in[12];
    const float* gleak    = (const float*)d_in[13];
    const float* cmt      = (const float*)d_in[14];
    float* out = (float*)d_out;

    // Workspace: Prec 1 MiB | Psen 512 KiB
    char* ws = (char*)d_ws;
    float4* Prec = (float4*)ws;
    float4* Psen = (float4*)(ws + (1u << 20));

    pack_kernel<<<(Nn * Nn + In * Nn + 255) / 256, 256, 0, stream>>>(
        mu, sigma, W, erev, smu, ssigma, sW, serev, Prec, Psen);

    ltc_fused_kernel<<<Bn / 4, 1024, 0, stream>>>(
        inputs, state, input_w, input_b, Psen, Prec, vleak, gleak, cmt, out);
}

// Round 6
// 179.955 us; speedup vs baseline: 1.5083x; 1.5083x over previous
//
#include <hip/hip_runtime.h>

// LTC cell: B=1024, I=128, N=256, 6 unfolds. Round 10: REVERT to the R0
// fully-fused kernel — the session's empirical optimum (114.4 us).
// Evidence across R0/R6/R7/R8/R9: VALUBusy*dur == 88-92 us in every variant
// (pure issue-bound; 1 exp + 1 rcp + 4 VALU + 1/4 load per sigmoid is the
// irreducible stream). All attempts to raise busy past 77% backfired:
//   R6 n-split+LLC sync  144us @61%   (sync latency)
//   R7 pairwise rcp      116us @77%   (trans savings == VALU additions)
//   R8 2 indep blocks    191us @54%   (2x L2 stream, latency exposed)
//   R9 quad+4way rcp     209us @44%   (fractured loads + serialized chain)
// R0's contiguous 1KB wave loads + 4 independent accumulator chains ARE the
// 77%-busy configuration. Each block: 4 batches x 256 neurons, 6 unfolds in
// one kernel, grid 256 = 1 block/CU.

#define LOG2E 1.44269504088896340f

constexpr int Bn = 1024;
constexpr int In = 128;
constexpr int Nn = 256;
constexpr int UNFOLDS = 6;

#if __has_builtin(__builtin_amdgcn_exp2f)
#define EXP2F(x) __builtin_amdgcn_exp2f(x)
#else
#define EXP2F(x) __exp2f(x)
#endif
#if __has_builtin(__builtin_amdgcn_rcpf)
#define RCPF(x) __builtin_amdgcn_rcpf(x)
#else
#define RCPF(x) (1.0f / (x))
#endif

// ---------------------------------------------------------------------------
// Pack: Prec[i*N+n] = {sigma*log2e, sigma*mu*log2e, W, W*erev}; same for Psen.
// sigmoid(sigma*(v-mu)) = 1/(1 + exp2(B - A*v)), A=sigma*log2e, B=sigma*mu*log2e.
// ---------------------------------------------------------------------------
__global__ __launch_bounds__(256) void pack_kernel(
    const float* __restrict__ mu, const float* __restrict__ sigma,
    const float* __restrict__ W, const float* __restrict__ erev,
    const float* __restrict__ smu, const float* __restrict__ ssigma,
    const float* __restrict__ sW, const float* __restrict__ serev,
    float4* __restrict__ Prec, float4* __restrict__ Psen) {
    int idx = blockIdx.x * 256 + threadIdx.x;
    if (idx < Nn * Nn) {
        float s = sigma[idx], m = mu[idx], w = W[idx], e = erev[idx];
        Prec[idx] = make_float4(s * LOG2E, s * m * LOG2E, w, w * e);
        return;
    }
    int j = idx - Nn * Nn;
    if (j < In * Nn) {
        float s = ssigma[j], m = smu[j], w = sW[j], e = serev[j];
        Psen[j] = make_float4(s * LOG2E, s * m * LOG2E, w, w * e);
    }
}

// ---------------------------------------------------------------------------
// Fused LTC kernel: sensory + 6 unfolds. Grid = 256 blocks x 1024 threads.
// ---------------------------------------------------------------------------
__global__ __launch_bounds__(1024, 1) void ltc_fused_kernel(
    const float* __restrict__ inputs, const float* __restrict__ state,
    const float* __restrict__ input_w, const float* __restrict__ input_b,
    const float4* __restrict__ Psen, const float4* __restrict__ Prec,
    const float* __restrict__ vleak, const float* __restrict__ gleak,
    const float* __restrict__ cmt, float* __restrict__ out) {
    __shared__ float4 vt[Nn];            // [i] -> 4 batches packed, 4 KB
    __shared__ float2 part[4][4][Nn];    // [ih][bb][n], 32 KB
    __shared__ float4 xs[In];            // sensory x, [i] -> 4 batches, 2 KB

    const int tid = threadIdx.x;
    const int b0 = blockIdx.x * 4;
    const int n = tid & 255;
    const int ih = tid >> 8;  // 0..3 : i-slice for compute, bb for reduce

    // ---- fill: v state (this thread's (bb=ih, n) value) + sensory x ----
    float vp = state[(b0 + ih) * Nn + n];      // coalesced
    ((float*)vt)[n * 4 + ih] = vp;
    if (tid < 4 * In) {
        int i = tid & 127, bb = tid >> 7;      // bb in 0..3
        ((float*)xs)[i * 4 + bb] =
            inputs[(b0 + bb) * In + i] * input_w[i] + input_b[i];
    }
    // leak params for this thread's n (wavefront-coalesced loads)
    const float g = gleak[n], c = cmt[n];
    const float gvl = g * vleak[n];
    __syncthreads();

    // ---- sensory sums (i = 0..127, slice 32 per ih) ----
    float sens_n, sens_d;
    {
        float num[4] = {0.f, 0.f, 0.f, 0.f};
        float den[4] = {0.f, 0.f, 0.f, 0.f};
        const float4* __restrict__ pp = Psen + n;
#pragma unroll 8
        for (int i = ih * 32; i < ih * 32 + 32; ++i) {
            float4 p = pp[i * Nn];   // coalesced dwordx4
            float4 v = xs[i];        // b128 broadcast (ih wave-uniform)
#pragma unroll
            for (int bb = 0; bb < 4; ++bb) {
                float vb = (bb == 0) ? v.x : (bb == 1) ? v.y : (bb == 2) ? v.z : v.w;
                float r = RCPF(1.0f + EXP2F(fmaf(-p.x, vb, p.y)));
                den[bb] += p.z * r;
                num[bb] += p.w * r;
            }
        }
#pragma unroll
        for (int bb = 0; bb < 4; ++bb)
            part[ih][bb][n] = make_float2(num[bb], den[bb]);
        __syncthreads();
        float wn = 0.f, wd = 0.f;
#pragma unroll
        for (int s = 0; s < 4; ++s) {
            float2 v = part[s][ih][n];  // this thread's bb == ih
            wn += v.x;
            wd += v.y;
        }
        sens_n = wn;
        sens_d = wd;
    }

    // ---- 6 unfolds ----
    const float4* __restrict__ pp = Prec + n;
    for (int s = 0; s < UNFOLDS; ++s) {
        __syncthreads();  // vt writes from prev step visible; part reusable
        float num[4] = {0.f, 0.f, 0.f, 0.f};
        float den[4] = {0.f, 0.f, 0.f, 0.f};
#pragma unroll 8
        for (int i = ih * 64; i < ih * 64 + 64; ++i) {
            float4 p = pp[i * Nn];   // coalesced dwordx4 (L2-resident stream)
            float4 v = vt[i];        // b128 broadcast
#pragma unroll
            for (int bb = 0; bb < 4; ++bb) {
                float vb = (bb == 0) ? v.x : (bb == 1) ? v.y : (bb == 2) ? v.z : v.w;
                float r = RCPF(1.0f + EXP2F(fmaf(-p.x, vb, p.y)));
                den[bb] += p.z * r;
                num[bb] += p.w * r;
            }
        }
#pragma unroll
        for (int bb = 0; bb < 4; ++bb)
            part[ih][bb][n] = make_float2(num[bb], den[bb]);
        __syncthreads();
        // reduce for this thread's (bb=ih, n)
        float wn = sens_n, wd = sens_d;
#pragma unroll
        for (int s2 = 0; s2 < 4; ++s2) {
            float2 v = part[s2][ih][n];
            wn += v.x;
            wd += v.y;
        }
        float res = (c * vp + gvl + wn) * RCPF(c + g + wd);
        vp = res;
        if (s == UNFOLDS - 1)
            out[(b0 + ih) * Nn + n] = res;       // coalesced final store
        else
            ((float*)vt)[n * 4 + ih] = res;
    }
}

// ---------------------------------------------------------------------------
extern "C" void kernel_launch(void* const* d_in, const int* in_sizes, int n_in,
                              void* d_out, int out_size, void* d_ws, size_t ws_size,
                              hipStream_t stream) {
    const float* inputs   = (const float*)d_in[0];
    const float* state    = (const float*)d_in[1];
    const float* input_w  = (const float*)d_in[2];
    const float* input_b  = (const float*)d_in[3];
    const float* smu      = (const float*)d_in[4];
    const float* ssigma   = (const float*)d_in[5];
    const float* sW       = (const float*)d_in[6];
    const float* serev    = (const float*)d_in[7];
    const float* mu       = (const float*)d_in[8];
    const float* sigma    = (const float*)d_in[9];
    const float* W        = (const float*)d_in[10];
    const float* erev     = (const float*)d_in[11];
    const float* vleak    = (const float*)d_in[12];
    const float* gleak    = (const float*)d_in[13];
    const float* cmt      = (const float*)d_in[14];
    float* out = (float*)d_out;

    // Workspace: Prec 1 MiB | Psen 512 KiB
    char* ws = (char*)d_ws;
    float4* Prec = (float4*)ws;
    float4* Psen = (float4*)(ws + (1u << 20));

    pack_kernel<<<(Nn * Nn + In * Nn + 255) / 256, 256, 0, stream>>>(
        mu, sigma, W, erev, smu, ssigma, sW, serev, Prec, Psen);

    ltc_fused_kernel<<<Bn / 4, 1024, 0, stream>>>(
        inputs, state, input_w, input_b, Psen, Prec, vleak, gleak, cmt, out);
}